// Round 1
// baseline (6653.243 us; speedup 1.0000x reference)
//
#include <hip/hip_runtime.h>

#define Bdim 640
#define Hdim 768
#define PJdim 256
#define Tdim 160

typedef _Float16 half8 __attribute__((ext_vector_type(8)));
typedef float floatx4 __attribute__((ext_vector_type(4)));

// ---------------- workspace layout (bytes) ----------------
// hbuf: 3 rotating bufs x 3 layers x B x PJ fp32
// c:    3 layers x B x H fp32
// WS:   repacked fp16 gate weights, per layer: [htile][kchunk][nn=256][kk=40]
//       (kk 32..39 = zero pad so LDS image == global image, conflict-free)
// PT:   P transposed fp16: [layer][pj=256][h=768]
constexpr size_t HBUF_BYTES = 3ull * 3 * Bdim * PJdim * 4;   // 5,898,240
constexpr size_t C_OFF      = HBUF_BYTES;
constexpr size_t C_BYTES    = 3ull * Bdim * Hdim * 4;        // 5,898,240
constexpr size_t WS_OFF     = C_OFF + C_BYTES;
constexpr size_t WS0_HALFS  = 12ull * 10 * 256 * 40;         // layer0: K=320 -> 10 chunks
constexpr size_t WS12_HALFS = 12ull * 16 * 256 * 40;         // layers1/2: K=512 -> 16 chunks
constexpr size_t WS_HALFS   = WS0_HALFS + 2 * WS12_HALFS;    // 5,160,960
constexpr size_t PT_OFF     = WS_OFF + WS_HALFS * 2;
constexpr size_t PT_HALFS   = 3ull * 256 * 768;              // 589,824

__device__ __forceinline__ float sigm(float v) { return 1.0f / (1.0f + __expf(-v)); }
__device__ __forceinline__ float tanh_fast(float v) { return 2.0f / (1.0f + __expf(-2.0f * v)) - 1.0f; }

// ---------------- one-time repack: W,P fp32 -> fp16, fragment-ready layout ----------------
__global__ void repack_kernel(const float* __restrict__ W0, const float* __restrict__ W1,
                              const float* __restrict__ W2, const float* __restrict__ P0,
                              const float* __restrict__ P1, const float* __restrict__ P2,
                              _Float16* __restrict__ WS, _Float16* __restrict__ PT)
{
    size_t idx = (size_t)blockIdx.x * 256 + threadIdx.x;
    if (idx < WS_HALFS) {
        size_t rem; int KC, K; const float* W;
        if (idx < WS0_HALFS)                  { rem = idx;                          KC = 10; K = 296; W = W0; }
        else if (idx < WS0_HALFS + WS12_HALFS){ rem = idx - WS0_HALFS;              KC = 16; K = 512; W = W1; }
        else                                  { rem = idx - WS0_HALFS - WS12_HALFS; KC = 16; K = 512; W = W2; }
        int kk = (int)(rem % 40); size_t r2 = rem / 40;
        int nn = (int)(r2 % 256); size_t r3 = r2 / 256;
        int kc = (int)(r3 % KC);  int ht = (int)(r3 / KC);
        float v = 0.0f;
        int k = kc * 32 + kk;
        if (kk < 32 && k < K) {
            int ng = (nn >> 6) * Hdim + ht * 64 + (nn & 63);   // gate-major column index
            v = W[(size_t)k * (4 * Hdim) + ng];
        }
        WS[idx] = (_Float16)v;
    } else if (idx < WS_HALFS + PT_HALFS) {
        size_t i2 = idx - WS_HALFS;
        int l = (int)(i2 / (256 * Hdim)); size_t rem = i2 % (256 * Hdim);
        int pj = (int)(rem / Hdim); int h = (int)(rem % Hdim);
        const float* P = (l == 0) ? P0 : (l == 1) ? P1 : P2;
        PT[i2] = (_Float16)P[(size_t)h * PJdim + pj];
    }
}

// ---------------- one pipeline step: layer l processes t = s - l ----------------
__global__ __launch_bounds__(256, 2)
void lstm_step(const float* __restrict__ x,
               const _Float16* __restrict__ WS, const _Float16* __restrict__ PT,
               const float* __restrict__ bias0, const float* __restrict__ bias1,
               const float* __restrict__ bias2,
               float* __restrict__ cst, float* __restrict__ hbuf, int s)
{
    __shared__ __align__(16) _Float16 Alds[64 * 40];    // A chunk  [row][k32 +8 pad]
    __shared__ __align__(16) _Float16 Wlds[256 * 40];   // W^T chunk [n][k32 +8 pad]
    __shared__ __align__(16) _Float16 Mlds[64 * 72];    // m tile   [row][h64 +8 pad]

    const int tid = threadIdx.x, bid = blockIdx.x;

    // ---- phase 0: zero the buffer step s+1 will atomically accumulate into (dead at step s)
    {
        float4* z4 = (float4*)(hbuf + (size_t)((s + 1) % 3) * (3 * Bdim * PJdim));
        const int n4 = 3 * Bdim * PJdim / 4;
        for (int i = bid * 256 + tid; i < n4; i += 360 * 256)
            z4[i] = make_float4(0.f, 0.f, 0.f, 0.f);
    }

    const int l = bid / 120;
    const int t = s - l;
    if (t < 0 || t >= Tdim) return;   // whole block inactive -> uniform exit

    const int tile = bid % 120;
    const int b0r = (tile % 10) * 64;
    const int ht  = tile / 10;
    const int h0  = ht * 64;
    const float* hrd  = hbuf + (size_t)((s + 2) % 3) * (3 * Bdim * PJdim);
    const float* hown = hrd + (size_t)l * Bdim * PJdim;
    const float* hin  = (l > 0) ? hrd + (size_t)(l - 1) * Bdim * PJdim : nullptr;
    const float* xt   = x + (size_t)t * Bdim * 40;
    const int KC = (l == 0) ? 10 : 16;
    const _Float16* Wg = WS + ((l == 0) ? 0ull : (l == 1) ? WS0_HALFS : WS0_HALFS + WS12_HALFS);
    const _Float16* Wslab = Wg + (size_t)ht * KC * 10240;
    const float* bias = (l == 0) ? bias0 : (l == 1) ? bias1 : bias2;

    const int wv = tid >> 6, lane = tid & 63, qd = lane >> 4, ln = lane & 15;
    const int arow = tid >> 2;            // 0..63, A-staging row
    const int gb = b0r + arow;            // global batch row
    const int kw = (tid & 3) * 8;         // 8-elem k-window within chunk

    floatx4 acc[16];                      // [g*4 + hs]
    const floatx4 fz = {0.f, 0.f, 0.f, 0.f};
#pragma unroll
    for (int i = 0; i < 16; i++) acc[i] = fz;

    // ================= gate GEMM: z[64, 4x64] = A[64,K] @ W[K, sel] =================
    for (int kc = 0; kc < KC; ++kc) {
        __syncthreads();
        // -- stage A chunk [64][32] (fp32 gather -> fp16), sources 8-aligned by construction
        {
            int kg = kc * 32 + kw;
            const float* src = nullptr;
            if (l == 0) {
                if (kg < 40)       src = xt + (size_t)gb * 40 + kg;
                else if (kg < 296) src = hown + (size_t)gb * PJdim + (kg - 40);
            } else {
                src = (kg < 256) ? hin + (size_t)gb * PJdim + kg
                                 : hown + (size_t)gb * PJdim + (kg - 256);
            }
            half8 hv;
            if (src) {
                const float4 u = ((const float4*)src)[0];
                const float4 w = ((const float4*)src)[1];
                hv[0] = (_Float16)u.x; hv[1] = (_Float16)u.y; hv[2] = (_Float16)u.z; hv[3] = (_Float16)u.w;
                hv[4] = (_Float16)w.x; hv[5] = (_Float16)w.y; hv[6] = (_Float16)w.z; hv[7] = (_Float16)w.w;
            } else {
#pragma unroll
                for (int e = 0; e < 8; e++) hv[e] = (_Float16)0.f;
            }
            *(half8*)&Alds[arow * 40 + kw] = hv;
        }
        // -- stage W chunk: flat 20480 B copy (global image == LDS image, pad included)
        {
            const half8* gsrc = (const half8*)(Wslab + (size_t)kc * 10240);
            half8* ldst = (half8*)Wlds;
#pragma unroll
            for (int i = 0; i < 5; i++)
                ldst[tid + 256 * i] = gsrc[tid + 256 * i];
        }
        __syncthreads();
        // -- MFMA: wave wv owns rows [16*wv, 16*wv+16), all 256 gate columns
        half8 af = *(const half8*)&Alds[(wv * 16 + ln) * 40 + qd * 8];
#pragma unroll
        for (int j = 0; j < 16; ++j) {
            half8 bf = *(const half8*)&Wlds[(j * 16 + ln) * 40 + qd * 8];
            acc[j] = __builtin_amdgcn_mfma_f32_16x16x32_f16(af, bf, acc[j], 0, 0, 0);
        }
    }

    // ================= elementwise LSTM update (gate order i,j,f,o) =================
#pragma unroll
    for (int hs = 0; hs < 4; ++hs) {
        const int hcol = h0 + hs * 16 + ln;
        const float bi = bias[hcol], bj = bias[Hdim + hcol];
        const float bff = bias[2 * Hdim + hcol], bo = bias[3 * Hdim + hcol];
#pragma unroll
        for (int r = 0; r < 4; ++r) {
            const int brow = b0r + wv * 16 + qd * 4 + r;
            float zi = acc[0 + hs][r] + bi;
            float zj = acc[4 + hs][r] + bj;
            float zf = acc[8 + hs][r] + bff;
            float zo = acc[12 + hs][r] + bo;
            float* cp = &cst[((size_t)l * Bdim + brow) * Hdim + hcol];
            float cn = sigm(zf + 1.0f) * (*cp) + sigm(zi) * tanh_fast(zj);
            *cp = cn;
            float m = sigm(zo) * tanh_fast(cn);
            Mlds[(wv * 16 + qd * 4 + r) * 72 + hs * 16 + ln] = (_Float16)m;
        }
    }

    // ================= projection: h += m[64,64] @ P[h-slice 64, 256] (split-K atomics) ====
    floatx4 pacc[16];
#pragma unroll
    for (int i = 0; i < 16; i++) pacc[i] = fz;
    for (int pc = 0; pc < 2; ++pc) {
        __syncthreads();   // pc=0: guards Mlds writes + old Wlds reads; pc=1: guards restage
        {
            const _Float16* pg = PT + ((size_t)l * 256 + tid) * Hdim + h0 + pc * 32;
#pragma unroll
            for (int i = 0; i < 4; i++)
                *(half8*)&Wlds[tid * 40 + i * 8] = *(const half8*)&pg[i * 8];
        }
        __syncthreads();
        half8 af = *(const half8*)&Mlds[(wv * 16 + ln) * 72 + pc * 32 + qd * 8];
#pragma unroll
        for (int j = 0; j < 16; ++j) {
            half8 bf = *(const half8*)&Wlds[(j * 16 + ln) * 40 + qd * 8];
            pacc[j] = __builtin_amdgcn_mfma_f32_16x16x32_f16(af, bf, pacc[j], 0, 0, 0);
        }
    }
    float* hw = hbuf + (size_t)(s % 3) * (3 * Bdim * PJdim) + (size_t)l * Bdim * PJdim;
#pragma unroll
    for (int j = 0; j < 16; ++j) {
#pragma unroll
        for (int r = 0; r < 4; ++r) {
            atomicAdd(&hw[(size_t)(b0r + wv * 16 + qd * 4 + r) * PJdim + j * 16 + ln], pacc[j][r]);
        }
    }
}

// ---------------- final L2 normalize of layer-2 h at t=159 (written into buffer 161%3==2) ----
__global__ void finalize_kernel(const float* __restrict__ hbuf, float* __restrict__ out)
{
    __shared__ float red[4];
    const int b = blockIdx.x, tid = threadIdx.x;
    const float* e = hbuf + (size_t)2 * (3 * Bdim * PJdim) + (size_t)2 * Bdim * PJdim + (size_t)b * PJdim;
    float v = e[tid];
    float ss = v * v;
#pragma unroll
    for (int o = 32; o > 0; o >>= 1) ss += __shfl_xor(ss, o, 64);
    if ((tid & 63) == 0) red[tid >> 6] = ss;
    __syncthreads();
    float tot = red[0] + red[1] + red[2] + red[3];
    float rs = rsqrtf(fmaxf(tot, 1e-12f));
    out[(size_t)b * PJdim + tid] = v * rs;
}

extern "C" void kernel_launch(void* const* d_in, const int* in_sizes, int n_in,
                              void* d_out, int out_size, void* d_ws, size_t ws_size,
                              hipStream_t stream)
{
    (void)in_sizes; (void)n_in; (void)out_size; (void)ws_size;
    const float* x  = (const float*)d_in[0];
    const float* W0 = (const float*)d_in[1];
    const float* b0 = (const float*)d_in[2];
    const float* P0 = (const float*)d_in[3];
    const float* W1 = (const float*)d_in[4];
    const float* b1 = (const float*)d_in[5];
    const float* P1 = (const float*)d_in[6];
    const float* W2 = (const float*)d_in[7];
    const float* b2 = (const float*)d_in[8];
    const float* P2 = (const float*)d_in[9];

    char* ws = (char*)d_ws;
    float* hbuf  = (float*)(ws);
    float* cst   = (float*)(ws + C_OFF);
    _Float16* WS = (_Float16*)(ws + WS_OFF);
    _Float16* PT = (_Float16*)(ws + PT_OFF);

    // zero initial h (all 3 rotating buffers) and c state
    hipMemsetAsync(ws, 0, HBUF_BYTES + C_BYTES, stream);

    {
        size_t total = WS_HALFS + PT_HALFS;
        int grid = (int)((total + 255) / 256);
        repack_kernel<<<grid, 256, 0, stream>>>(W0, W1, W2, P0, P1, P2, WS, PT);
    }

    // wavefront pipeline: step s runs layer l on timestep t=s-l; 3 cells in parallel
    for (int s = 0; s < Tdim + 2; ++s)
        lstm_step<<<360, 256, 0, stream>>>(x, WS, PT, b0, b1, b2, cst, hbuf, s);

    finalize_kernel<<<Bdim, 256, 0, stream>>>(hbuf, (float*)d_out);
}